// Round 9
// baseline (230.431 us; speedup 1.0000x reference)
//
#include <hip/hip_runtime.h>

#define TPB 256
#define PROWS 32

typedef unsigned int uint32;
typedef unsigned short ushort16;

// ---------------------------------------------------------------------------
// helpers
// ---------------------------------------------------------------------------
__device__ __forceinline__ unsigned short f2bf(float f) {
  union { float f; unsigned int i; } c; c.f = f;
  unsigned int r = c.i + 0x7fffu + ((c.i >> 16) & 1u);   // RNE
  return (unsigned short)(r >> 16);
}

__device__ __forceinline__ float bflo(uint32 p) {   // low bf16 of packed pair
  union { unsigned int i; float f; } c; c.i = p << 16; return c.f;
}
__device__ __forceinline__ float bfhi(uint32 p) {   // high bf16 of packed pair
  union { unsigned int i; float f; } c; c.i = p & 0xffff0000u; return c.f;
}

// zero two buffers in one dispatch
__global__ void zero2_kernel(int* __restrict__ a, int na, int* __restrict__ b, int nb) {
  int i = blockIdx.x * blockDim.x + threadIdx.x;
  int stride = gridDim.x * blockDim.x;
  for (int j = i; j < na; j += stride) a[j] = 0;
  for (int j = i; j < nb; j += stride) b[j] = 0;
}

// ---------------------------------------------------------------------------
// graph preprocessing: degrees + per-edge rank, norm, CSR-by-dst
// ---------------------------------------------------------------------------
__global__ void count_rank_kernel(const int* __restrict__ dst, int E,
                                  int* __restrict__ deg, int* __restrict__ rank) {
  int i = blockIdx.x * blockDim.x + threadIdx.x;
  if (i < E) rank[i] = atomicAdd(&deg[dst[i]], 1);
}

__global__ void dinv_kernel(const int* __restrict__ deg, int n, float* __restrict__ dinv) {
  int i = blockIdx.x * blockDim.x + threadIdx.x;
  if (i < n) dinv[i] = 1.0f / sqrtf((float)(deg[i] + 1));  // +1 self-loop
}

// block-wise exclusive scan; also emits per-block total
__global__ void scan_block_kernel(const int* __restrict__ in, int n,
                                  int* __restrict__ out_excl, int* __restrict__ bsum) {
  __shared__ int sh[TPB];
  int t = threadIdx.x;
  int i = blockIdx.x * TPB + t;
  int v = (i < n) ? in[i] : 0;
  sh[t] = v;
  __syncthreads();
  for (int off = 1; off < TPB; off <<= 1) {
    int x = (t >= off) ? sh[t - off] : 0;
    __syncthreads();
    sh[t] += x;
    __syncthreads();
  }
  if (i < n) out_excl[i] = sh[t] - v;          // exclusive
  if (t == TPB - 1 && bsum != nullptr) bsum[blockIdx.x] = sh[t];
}

__global__ void scan_fixup_kernel(int* __restrict__ rs, const int* __restrict__ boff,
                                  int n, int total) {
  int i = blockIdx.x * TPB + threadIdx.x;
  if (i < n) rs[i] += boff[blockIdx.x];
  else if (i == n) rs[n] = total;
}

// atomic-free placement: col[rs[d] + rank[i]] = src[i]
__global__ void fill_kernel(const int* __restrict__ src, const int* __restrict__ dst,
                            const int* __restrict__ rank, const int* __restrict__ rs,
                            int E, int* __restrict__ col) {
  int i = blockIdx.x * blockDim.x + threadIdx.x;
  if (i < E) {
    int d = dst[i];
    col[rs[d] + rank[i]] = src[i];
  }
}

// ---------------------------------------------------------------------------
// GEMM: zws[N,128](bf16) = dinv[r] * (A[N,128](f32) @ W[128,128](f32))
// A-tile k-index XOR-swizzled by row so b128 reads are conflict-free.
// ---------------------------------------------------------------------------
__global__ __launch_bounds__(256) void gemm128_kernel(const float* __restrict__ A,
                                                      const float* __restrict__ W,
                                                      const float* __restrict__ dinv,
                                                      ushort16* __restrict__ out, int nrows) {
  __shared__ float Wl[128 * 128];   // 64 KB
  __shared__ float Al[32 * 128];    // 16 KB (swizzled)
  int t = threadIdx.x;
  {
    const float4* __restrict__ W4 = (const float4*)W;
    float4* Wl4 = (float4*)Wl;
#pragma unroll
    for (int i = 0; i < 16; ++i) Wl4[t + 256 * i] = W4[t + 256 * i];
  }
  int r0 = blockIdx.x * 32;
  {
    const float4* __restrict__ A4 = (const float4*)A;
#pragma unroll
    for (int i = 0; i < 4; ++i) {
      int idx = t + 256 * i;        // 0..1023
      int r = idx >> 5;             // 0..31
      int cc = idx & 31;            // float4 index within row
      float4 v = make_float4(0.f, 0.f, 0.f, 0.f);
      if (r0 + r < nrows) v = A4[(size_t)(r0 + r) * 32 + cc];
      *(float4*)&Al[r * 128 + ((cc * 4) ^ ((r & 7) << 2))] = v;
    }
  }
  __syncthreads();

  int c4 = (t & 31) * 4;            // output cols c4..c4+3
  int rg = (t >> 5) * 4;            // output rows rg..rg+3 (local)
  float4 acc0 = {0, 0, 0, 0}, acc1 = {0, 0, 0, 0}, acc2 = {0, 0, 0, 0}, acc3 = {0, 0, 0, 0};
#pragma unroll 4
  for (int kk = 0; kk < 128; kk += 4) {
    float4 a0 = *(const float4*)&Al[(rg + 0) * 128 + (kk ^ (((rg + 0) & 7) << 2))];
    float4 a1 = *(const float4*)&Al[(rg + 1) * 128 + (kk ^ (((rg + 1) & 7) << 2))];
    float4 a2 = *(const float4*)&Al[(rg + 2) * 128 + (kk ^ (((rg + 2) & 7) << 2))];
    float4 a3 = *(const float4*)&Al[(rg + 3) * 128 + (kk ^ (((rg + 3) & 7) << 2))];
    float4 w0 = *(const float4*)&Wl[(kk + 0) * 128 + c4];
    float4 w1 = *(const float4*)&Wl[(kk + 1) * 128 + c4];
    float4 w2 = *(const float4*)&Wl[(kk + 2) * 128 + c4];
    float4 w3 = *(const float4*)&Wl[(kk + 3) * 128 + c4];
    acc0.x += w0.x*a0.x + w1.x*a0.y + w2.x*a0.z + w3.x*a0.w;
    acc0.y += w0.y*a0.x + w1.y*a0.y + w2.y*a0.z + w3.y*a0.w;
    acc0.z += w0.z*a0.x + w1.z*a0.y + w2.z*a0.z + w3.z*a0.w;
    acc0.w += w0.w*a0.x + w1.w*a0.y + w2.w*a0.z + w3.w*a0.w;
    acc1.x += w0.x*a1.x + w1.x*a1.y + w2.x*a1.z + w3.x*a1.w;
    acc1.y += w0.y*a1.x + w1.y*a1.y + w2.y*a1.z + w3.y*a1.w;
    acc1.z += w0.z*a1.x + w1.z*a1.y + w2.z*a1.z + w3.z*a1.w;
    acc1.w += w0.w*a1.x + w1.w*a1.y + w2.w*a1.z + w3.w*a1.w;
    acc2.x += w0.x*a2.x + w1.x*a2.y + w2.x*a2.z + w3.x*a2.w;
    acc2.y += w0.y*a2.x + w1.y*a2.y + w2.y*a2.z + w3.y*a2.w;
    acc2.z += w0.z*a2.x + w1.z*a2.y + w2.z*a2.z + w3.z*a2.w;
    acc2.w += w0.w*a2.x + w1.w*a2.y + w2.w*a2.z + w3.w*a2.w;
    acc3.x += w0.x*a3.x + w1.x*a3.y + w2.x*a3.z + w3.x*a3.w;
    acc3.y += w0.y*a3.x + w1.y*a3.y + w2.y*a3.z + w3.y*a3.w;
    acc3.z += w0.z*a3.x + w1.z*a3.y + w2.z*a3.z + w3.z*a3.w;
    acc3.w += w0.w*a3.x + w1.w*a3.y + w2.w*a3.z + w3.w*a3.w;
  }
  int r = r0 + rg;
#pragma unroll
  for (int rr = 0; rr < 4; ++rr) {
    float4 acc = (rr == 0) ? acc0 : (rr == 1) ? acc1 : (rr == 2) ? acc2 : acc3;
    if (r + rr < nrows) {
      float di = dinv[r + rr];
      ushort4 p;
      p.x = f2bf(di * acc.x); p.y = f2bf(di * acc.y);
      p.z = f2bf(di * acc.z); p.w = f2bf(di * acc.w);
      *(ushort4*)&out[(size_t)(r + rr) * 128 + c4] = p;
    }
  }
}

// ---------------------------------------------------------------------------
// aggregation (R7 proven version): out[n] = prelu( dinv[n]*( zws[n] + sum ) + b )
// one wave per node; wave-cooperative col staging, uniform shfl broadcast.
// ---------------------------------------------------------------------------
__global__ __launch_bounds__(256) void aggregate_kernel(
    const ushort16* __restrict__ zws, const int* __restrict__ rs,
    const int* __restrict__ col,
    const float* __restrict__ dinv, const float* __restrict__ bias,
    const float* __restrict__ alpha, float* __restrict__ out, int nrows) {
  int wid = threadIdx.x >> 6;
  int lane = threadIdx.x & 63;
  int node = blockIdx.x * 4 + wid;
  if (node >= nrows) return;
  int c = lane * 2;

  uint32 pv = *(const uint32*)&zws[(size_t)node * 128 + c];
  float accx = bflo(pv), accy = bfhi(pv);

  int e0 = rs[node], e1 = rs[node + 1];
  for (int base = e0; base < e1; base += 64) {
    int nb = e1 - base; if (nb > 64) nb = 64;
    int colv = (base + lane < e1) ? col[base + lane] : 0;   // one coalesced load
    int j = 0;
    for (; j + 8 <= nb; j += 8) {
      int s0 = __shfl(colv, j + 0);
      int s1 = __shfl(colv, j + 1);
      int s2 = __shfl(colv, j + 2);
      int s3 = __shfl(colv, j + 3);
      int s4 = __shfl(colv, j + 4);
      int s5 = __shfl(colv, j + 5);
      int s6 = __shfl(colv, j + 6);
      int s7 = __shfl(colv, j + 7);
      uint32 p0 = *(const uint32*)&zws[(size_t)s0 * 128 + c];
      uint32 p1 = *(const uint32*)&zws[(size_t)s1 * 128 + c];
      uint32 p2 = *(const uint32*)&zws[(size_t)s2 * 128 + c];
      uint32 p3 = *(const uint32*)&zws[(size_t)s3 * 128 + c];
      uint32 p4 = *(const uint32*)&zws[(size_t)s4 * 128 + c];
      uint32 p5 = *(const uint32*)&zws[(size_t)s5 * 128 + c];
      uint32 p6 = *(const uint32*)&zws[(size_t)s6 * 128 + c];
      uint32 p7 = *(const uint32*)&zws[(size_t)s7 * 128 + c];
      accx += bflo(p0) + bflo(p1) + bflo(p2) + bflo(p3)
            + bflo(p4) + bflo(p5) + bflo(p6) + bflo(p7);
      accy += bfhi(p0) + bfhi(p1) + bfhi(p2) + bfhi(p3)
            + bfhi(p4) + bfhi(p5) + bfhi(p6) + bfhi(p7);
    }
    for (; j < nb; ++j) {
      int s = __shfl(colv, j);
      uint32 p = *(const uint32*)&zws[(size_t)s * 128 + c];
      accx += bflo(p);
      accy += bfhi(p);
    }
  }

  float di = dinv[node];
  float2 b = *(const float2*)&bias[c];
  float2 al = *(const float2*)&alpha[c];
  float zx = di * accx + b.x, zy = di * accy + b.y;
  zx = zx > 0.f ? zx : al.x * zx;
  zy = zy > 0.f ? zy : al.y * zy;
  float2 r; r.x = zx; r.y = zy;
  *(float2*)&out[(size_t)node * 128 + c] = r;
}

// ---------------------------------------------------------------------------
// pooling: g[gi] = [ sum_{batch[n]==gi} z1[n] | sum z2[n] ]  (batch sorted)
// ---------------------------------------------------------------------------
__global__ __launch_bounds__(256) void pool_kernel(const float* __restrict__ z1,
                                                   const float* __restrict__ z2,
                                                   const int* __restrict__ batch, int n,
                                                   float* __restrict__ g) {
  int r0 = blockIdx.x * PROWS;
  int t = threadIdx.x;
  __shared__ int bsh[PROWS];
  int rmax = n - r0; if (rmax > PROWS) rmax = PROWS;
  if (t < PROWS && t < rmax) bsh[t] = batch[r0 + t];
  __syncthreads();

  int c = t & 127;
  const float* __restrict__ src = (t < 128) ? z1 : z2;
  float acc = 0.f;
  int cur = bsh[0];
  for (int i = 0; i < rmax; ++i) {
    int b = bsh[i];
    if (b != cur) {
      atomicAdd(&g[(size_t)cur * 256 + t], acc);
      acc = 0.f;
      cur = b;
    }
    acc += src[(size_t)(r0 + i) * 128 + c];
  }
  atomicAdd(&g[(size_t)cur * 256 + t], acc);
}

// ---------------------------------------------------------------------------
// launcher
// ---------------------------------------------------------------------------
extern "C" void kernel_launch(void* const* d_in, const int* in_sizes, int n_in,
                              void* d_out, int out_size, void* d_ws, size_t ws_size,
                              hipStream_t stream) {
  const float* x     = (const float*)d_in[0];
  const int*   ei    = (const int*)d_in[1];
  const int*   batch = (const int*)d_in[2];
  const float* W0    = (const float*)d_in[3];
  const float* b0    = (const float*)d_in[4];
  const float* a0    = (const float*)d_in[5];
  const float* W1    = (const float*)d_in[6];
  const float* b1    = (const float*)d_in[7];
  const float* a1    = (const float*)d_in[8];
  float* out = (float*)d_out;

  const int N = in_sizes[0] / 128;
  const int E = in_sizes[1] / 2;
  const int G = (out_size - N * 128) / 256;

  const int* src  = ei;       // edge_index[0]
  const int* dstp = ei + E;   // edge_index[1]

  // workspace layout (4-byte words)
  int* w = (int*)d_ws;
  size_t o = 0;
  int*      deg    = w + o; o += (size_t)N;
  int*      rs     = w + o; o += (size_t)((N + 1 + 3) & ~3);
  int*      bsum   = w + o; o += 256;
  int*      boff   = w + o; o += 256;
  int*      col    = w + o; o += (size_t)E;
  int*      rank   = w + o; o += (size_t)E;
  float*    dinv   = (float*)(w + o); o += (size_t)N;
  ushort16* zws    = (ushort16*)(w + o); o += (size_t)N * 64;   // bf16 [N,128]
  float*    z1     = (float*)(w + o); o += (size_t)N * 128;
  (void)ws_size; (void)n_in;

  const int blkE = (E + TPB - 1) / TPB;
  const int blkN = (N + TPB - 1) / TPB;   // also #scan blocks (<= 256 for N<=65536)

  float* g = out + (size_t)N * 128;

  // zero deg + pooled-output region in one cheap dispatch
  zero2_kernel<<<512, TPB, 0, stream>>>(deg, N, (int*)g, G * 256);

  // degrees + per-edge rank -> dinv
  count_rank_kernel<<<blkE, TPB, 0, stream>>>(dstp, E, deg, rank);
  dinv_kernel<<<blkN, TPB, 0, stream>>>(deg, N, dinv);

  // exclusive scan of deg -> row_start (rs), hierarchical
  scan_block_kernel<<<blkN, TPB, 0, stream>>>(deg, N, rs, bsum);
  scan_block_kernel<<<1, TPB, 0, stream>>>(bsum, blkN, boff, nullptr);
  scan_fixup_kernel<<<(N + TPB) / TPB, TPB, 0, stream>>>(rs, boff, N, E);

  // CSR fill (atomic-free)
  fill_kernel<<<blkE, TPB, 0, stream>>>(src, dstp, rank, rs, E, col);

  // layer 0: zws = bf16(dinv * (x @ W0)) ; z1 = prelu(dinv*(zws_self + sum) + b0)
  gemm128_kernel<<<(N + 31) / 32, 256, 0, stream>>>(x, W0, dinv, zws, N);
  aggregate_kernel<<<(N + 3) / 4, 256, 0, stream>>>(zws, rs, col, dinv, b0, a0, z1, N);

  // layer 1
  gemm128_kernel<<<(N + 31) / 32, 256, 0, stream>>>(z1, W1, dinv, zws, N);
  aggregate_kernel<<<(N + 3) / 4, 256, 0, stream>>>(zws, rs, col, dinv, b1, a1, out, N);

  // pooling -> g
  pool_kernel<<<(N + PROWS - 1) / PROWS, 256, 0, stream>>>(z1, out, batch, N, g);
}

// Round 10
// 228.330 us; speedup vs baseline: 1.0092x; 1.0092x over previous
//
#include <hip/hip_runtime.h>

#define TPB 256
#define PROWS 32

typedef unsigned int uint32;
typedef unsigned short ushort16;

// ---------------------------------------------------------------------------
// helpers
// ---------------------------------------------------------------------------
__device__ __forceinline__ unsigned short f2bf(float f) {
  union { float f; unsigned int i; } c; c.f = f;
  unsigned int r = c.i + 0x7fffu + ((c.i >> 16) & 1u);   // RNE
  return (unsigned short)(r >> 16);
}

__device__ __forceinline__ float bflo(uint32 p) {   // low bf16 of packed pair
  union { unsigned int i; float f; } c; c.i = p << 16; return c.f;
}
__device__ __forceinline__ float bfhi(uint32 p) {   // high bf16 of packed pair
  union { unsigned int i; float f; } c; c.i = p & 0xffff0000u; return c.f;
}

// zero two buffers in one dispatch
__global__ void zero2_kernel(int* __restrict__ a, int na, int* __restrict__ b, int nb) {
  int i = blockIdx.x * blockDim.x + threadIdx.x;
  int stride = gridDim.x * blockDim.x;
  for (int j = i; j < na; j += stride) a[j] = 0;
  for (int j = i; j < nb; j += stride) b[j] = 0;
}

// ---------------------------------------------------------------------------
// graph preprocessing: degrees + per-edge rank, norm, CSR-by-dst
// ---------------------------------------------------------------------------
__global__ void count_rank_kernel(const int* __restrict__ dst, int E,
                                  int* __restrict__ deg, int* __restrict__ rank) {
  int i = blockIdx.x * blockDim.x + threadIdx.x;
  if (i < E) rank[i] = atomicAdd(&deg[dst[i]], 1);
}

__global__ void dinv_kernel(const int* __restrict__ deg, int n, float* __restrict__ dinv) {
  int i = blockIdx.x * blockDim.x + threadIdx.x;
  if (i < n) dinv[i] = 1.0f / sqrtf((float)(deg[i] + 1));  // +1 self-loop
}

// block-wise exclusive scan; also emits per-block total
__global__ void scan_block_kernel(const int* __restrict__ in, int n,
                                  int* __restrict__ out_excl, int* __restrict__ bsum) {
  __shared__ int sh[TPB];
  int t = threadIdx.x;
  int i = blockIdx.x * TPB + t;
  int v = (i < n) ? in[i] : 0;
  sh[t] = v;
  __syncthreads();
  for (int off = 1; off < TPB; off <<= 1) {
    int x = (t >= off) ? sh[t - off] : 0;
    __syncthreads();
    sh[t] += x;
    __syncthreads();
  }
  if (i < n) out_excl[i] = sh[t] - v;          // exclusive
  if (t == TPB - 1 && bsum != nullptr) bsum[blockIdx.x] = sh[t];
}

__global__ void scan_fixup_kernel(int* __restrict__ rs, const int* __restrict__ boff,
                                  int n, int total) {
  int i = blockIdx.x * TPB + threadIdx.x;
  if (i < n) rs[i] += boff[blockIdx.x];
  else if (i == n) rs[n] = total;
}

// atomic-free placement: col[rs[d] + rank[i]] = src[i]
__global__ void fill_kernel(const int* __restrict__ src, const int* __restrict__ dst,
                            const int* __restrict__ rank, const int* __restrict__ rs,
                            int E, int* __restrict__ col) {
  int i = blockIdx.x * blockDim.x + threadIdx.x;
  if (i < E) {
    int d = dst[i];
    col[rs[d] + rank[i]] = src[i];
  }
}

// ---------------------------------------------------------------------------
// GEMM: zws[N,128](bf16) = dinv[r] * (A[N,128](f32) @ W[128,128](f32))
// A-tile (16 KB) in LDS; W read directly from global (L1/L2-hot, broadcast
// across blocks). LDS 80KB->16KB lifts the 2-block/CU occupancy cap.
// ---------------------------------------------------------------------------
__global__ __launch_bounds__(256) void gemm128_kernel(const float* __restrict__ A,
                                                      const float* __restrict__ W,
                                                      const float* __restrict__ dinv,
                                                      ushort16* __restrict__ out, int nrows) {
  __shared__ float Al[32][128];     // 16 KB
  int t = threadIdx.x;
  int r0 = blockIdx.x * 32;
  {
    const float4* __restrict__ A4 = (const float4*)A;
#pragma unroll
    for (int i = 0; i < 4; ++i) {
      int idx = t + 256 * i;        // 0..1023
      int r = idx >> 5;             // 0..31
      int cc = idx & 31;            // float4 index within row
      float4 v = make_float4(0.f, 0.f, 0.f, 0.f);
      if (r0 + r < nrows) v = A4[(size_t)(r0 + r) * 32 + cc];
      *(float4*)&Al[r][cc * 4] = v;
    }
  }
  __syncthreads();

  const float4* __restrict__ W4 = (const float4*)W;   // [128][32] float4 view
  int c4l = t & 31;                 // float4 col index (cols c4l*4 .. +3)
  int rg = (t >> 5) * 4;            // output rows rg..rg+3 (local)
  float4 acc0 = {0, 0, 0, 0}, acc1 = {0, 0, 0, 0}, acc2 = {0, 0, 0, 0}, acc3 = {0, 0, 0, 0};
#pragma unroll 8
  for (int k = 0; k < 128; ++k) {
    float4 w = W4[k * 32 + c4l];    // coalesced 512B/wave, L1-hot
    float a0 = Al[rg + 0][k];
    float a1 = Al[rg + 1][k];
    float a2 = Al[rg + 2][k];
    float a3 = Al[rg + 3][k];
    acc0.x += w.x * a0; acc0.y += w.y * a0; acc0.z += w.z * a0; acc0.w += w.w * a0;
    acc1.x += w.x * a1; acc1.y += w.y * a1; acc1.z += w.z * a1; acc1.w += w.w * a1;
    acc2.x += w.x * a2; acc2.y += w.y * a2; acc2.z += w.z * a2; acc2.w += w.w * a2;
    acc3.x += w.x * a3; acc3.y += w.y * a3; acc3.z += w.z * a3; acc3.w += w.w * a3;
  }
  int c4 = c4l * 4;
  int r = r0 + rg;
#pragma unroll
  for (int rr = 0; rr < 4; ++rr) {
    float4 acc = (rr == 0) ? acc0 : (rr == 1) ? acc1 : (rr == 2) ? acc2 : acc3;
    if (r + rr < nrows) {
      float di = dinv[r + rr];
      ushort4 p;
      p.x = f2bf(di * acc.x); p.y = f2bf(di * acc.y);
      p.z = f2bf(di * acc.z); p.w = f2bf(di * acc.w);
      *(ushort4*)&out[(size_t)(r + rr) * 128 + c4] = p;
    }
  }
}

// ---------------------------------------------------------------------------
// aggregation (R7 proven version): out[n] = prelu( dinv[n]*( zws[n] + sum ) + b )
// one wave per node; wave-cooperative col staging, uniform shfl broadcast.
// ---------------------------------------------------------------------------
__global__ __launch_bounds__(256) void aggregate_kernel(
    const ushort16* __restrict__ zws, const int* __restrict__ rs,
    const int* __restrict__ col,
    const float* __restrict__ dinv, const float* __restrict__ bias,
    const float* __restrict__ alpha, float* __restrict__ out, int nrows) {
  int wid = threadIdx.x >> 6;
  int lane = threadIdx.x & 63;
  int node = blockIdx.x * 4 + wid;
  if (node >= nrows) return;
  int c = lane * 2;

  uint32 pv = *(const uint32*)&zws[(size_t)node * 128 + c];
  float accx = bflo(pv), accy = bfhi(pv);

  int e0 = rs[node], e1 = rs[node + 1];
  for (int base = e0; base < e1; base += 64) {
    int nb = e1 - base; if (nb > 64) nb = 64;
    int colv = (base + lane < e1) ? col[base + lane] : 0;   // one coalesced load
    int j = 0;
    for (; j + 8 <= nb; j += 8) {
      int s0 = __shfl(colv, j + 0);
      int s1 = __shfl(colv, j + 1);
      int s2 = __shfl(colv, j + 2);
      int s3 = __shfl(colv, j + 3);
      int s4 = __shfl(colv, j + 4);
      int s5 = __shfl(colv, j + 5);
      int s6 = __shfl(colv, j + 6);
      int s7 = __shfl(colv, j + 7);
      uint32 p0 = *(const uint32*)&zws[(size_t)s0 * 128 + c];
      uint32 p1 = *(const uint32*)&zws[(size_t)s1 * 128 + c];
      uint32 p2 = *(const uint32*)&zws[(size_t)s2 * 128 + c];
      uint32 p3 = *(const uint32*)&zws[(size_t)s3 * 128 + c];
      uint32 p4 = *(const uint32*)&zws[(size_t)s4 * 128 + c];
      uint32 p5 = *(const uint32*)&zws[(size_t)s5 * 128 + c];
      uint32 p6 = *(const uint32*)&zws[(size_t)s6 * 128 + c];
      uint32 p7 = *(const uint32*)&zws[(size_t)s7 * 128 + c];
      accx += bflo(p0) + bflo(p1) + bflo(p2) + bflo(p3)
            + bflo(p4) + bflo(p5) + bflo(p6) + bflo(p7);
      accy += bfhi(p0) + bfhi(p1) + bfhi(p2) + bfhi(p3)
            + bfhi(p4) + bfhi(p5) + bfhi(p6) + bfhi(p7);
    }
    for (; j < nb; ++j) {
      int s = __shfl(colv, j);
      uint32 p = *(const uint32*)&zws[(size_t)s * 128 + c];
      accx += bflo(p);
      accy += bfhi(p);
    }
  }

  float di = dinv[node];
  float2 b = *(const float2*)&bias[c];
  float2 al = *(const float2*)&alpha[c];
  float zx = di * accx + b.x, zy = di * accy + b.y;
  zx = zx > 0.f ? zx : al.x * zx;
  zy = zy > 0.f ? zy : al.y * zy;
  float2 r; r.x = zx; r.y = zy;
  *(float2*)&out[(size_t)node * 128 + c] = r;
}

// ---------------------------------------------------------------------------
// pooling: g[gi] = [ sum_{batch[n]==gi} z1[n] | sum z2[n] ]  (batch sorted)
// ---------------------------------------------------------------------------
__global__ __launch_bounds__(256) void pool_kernel(const float* __restrict__ z1,
                                                   const float* __restrict__ z2,
                                                   const int* __restrict__ batch, int n,
                                                   float* __restrict__ g) {
  int r0 = blockIdx.x * PROWS;
  int t = threadIdx.x;
  __shared__ int bsh[PROWS];
  int rmax = n - r0; if (rmax > PROWS) rmax = PROWS;
  if (t < PROWS && t < rmax) bsh[t] = batch[r0 + t];
  __syncthreads();

  int c = t & 127;
  const float* __restrict__ src = (t < 128) ? z1 : z2;
  float acc = 0.f;
  int cur = bsh[0];
  for (int i = 0; i < rmax; ++i) {
    int b = bsh[i];
    if (b != cur) {
      atomicAdd(&g[(size_t)cur * 256 + t], acc);
      acc = 0.f;
      cur = b;
    }
    acc += src[(size_t)(r0 + i) * 128 + c];
  }
  atomicAdd(&g[(size_t)cur * 256 + t], acc);
}

// ---------------------------------------------------------------------------
// launcher
// ---------------------------------------------------------------------------
extern "C" void kernel_launch(void* const* d_in, const int* in_sizes, int n_in,
                              void* d_out, int out_size, void* d_ws, size_t ws_size,
                              hipStream_t stream) {
  const float* x     = (const float*)d_in[0];
  const int*   ei    = (const int*)d_in[1];
  const int*   batch = (const int*)d_in[2];
  const float* W0    = (const float*)d_in[3];
  const float* b0    = (const float*)d_in[4];
  const float* a0    = (const float*)d_in[5];
  const float* W1    = (const float*)d_in[6];
  const float* b1    = (const float*)d_in[7];
  const float* a1    = (const float*)d_in[8];
  float* out = (float*)d_out;

  const int N = in_sizes[0] / 128;
  const int E = in_sizes[1] / 2;
  const int G = (out_size - N * 128) / 256;

  const int* src  = ei;       // edge_index[0]
  const int* dstp = ei + E;   // edge_index[1]

  // workspace layout (4-byte words)
  int* w = (int*)d_ws;
  size_t o = 0;
  int*      deg    = w + o; o += (size_t)N;
  int*      rs     = w + o; o += (size_t)((N + 1 + 3) & ~3);
  int*      bsum   = w + o; o += 256;
  int*      boff   = w + o; o += 256;
  int*      col    = w + o; o += (size_t)E;
  int*      rank   = w + o; o += (size_t)E;
  float*    dinv   = (float*)(w + o); o += (size_t)N;
  ushort16* zws    = (ushort16*)(w + o); o += (size_t)N * 64;   // bf16 [N,128]
  float*    z1     = (float*)(w + o); o += (size_t)N * 128;
  (void)ws_size; (void)n_in;

  const int blkE = (E + TPB - 1) / TPB;
  const int blkN = (N + TPB - 1) / TPB;   // also #scan blocks (<= 256 for N<=65536)

  float* g = out + (size_t)N * 128;

  // zero deg + pooled-output region in one cheap dispatch
  zero2_kernel<<<512, TPB, 0, stream>>>(deg, N, (int*)g, G * 256);

  // degrees + per-edge rank -> dinv
  count_rank_kernel<<<blkE, TPB, 0, stream>>>(dstp, E, deg, rank);
  dinv_kernel<<<blkN, TPB, 0, stream>>>(deg, N, dinv);

  // exclusive scan of deg -> row_start (rs), hierarchical
  scan_block_kernel<<<blkN, TPB, 0, stream>>>(deg, N, rs, bsum);
  scan_block_kernel<<<1, TPB, 0, stream>>>(bsum, blkN, boff, nullptr);
  scan_fixup_kernel<<<(N + TPB) / TPB, TPB, 0, stream>>>(rs, boff, N, E);

  // CSR fill (atomic-free)
  fill_kernel<<<blkE, TPB, 0, stream>>>(src, dstp, rank, rs, E, col);

  // layer 0: zws = bf16(dinv * (x @ W0)) ; z1 = prelu(dinv*(zws_self + sum) + b0)
  gemm128_kernel<<<(N + 31) / 32, 256, 0, stream>>>(x, W0, dinv, zws, N);
  aggregate_kernel<<<(N + 3) / 4, 256, 0, stream>>>(zws, rs, col, dinv, b0, a0, z1, N);

  // layer 1
  gemm128_kernel<<<(N + 31) / 32, 256, 0, stream>>>(z1, W1, dinv, zws, N);
  aggregate_kernel<<<(N + 3) / 4, 256, 0, stream>>>(zws, rs, col, dinv, b1, a1, out, N);

  // pooling -> g
  pool_kernel<<<(N + PROWS - 1) / PROWS, 256, 0, stream>>>(z1, out, batch, N, g);
}

// Round 11
// 206.756 us; speedup vs baseline: 1.1145x; 1.1043x over previous
//
#include <hip/hip_runtime.h>

#define TPB 256
#define PROWS 32

typedef unsigned int uint32;
typedef unsigned short ushort16;

typedef __attribute__((ext_vector_type(8))) short bf16x8;
typedef __attribute__((ext_vector_type(4))) float f32x4;

// ---------------------------------------------------------------------------
// helpers
// ---------------------------------------------------------------------------
__device__ __forceinline__ unsigned short f2bf(float f) {
  union { float f; unsigned int i; } c; c.f = f;
  unsigned int r = c.i + 0x7fffu + ((c.i >> 16) & 1u);   // RNE
  return (unsigned short)(r >> 16);
}

__device__ __forceinline__ float bflo(uint32 p) {   // low bf16 of packed pair
  union { unsigned int i; float f; } c; c.i = p << 16; return c.f;
}
__device__ __forceinline__ float bfhi(uint32 p) {   // high bf16 of packed pair
  union { unsigned int i; float f; } c; c.i = p & 0xffff0000u; return c.f;
}

// zero two buffers in one dispatch
__global__ void zero2_kernel(int* __restrict__ a, int na, int* __restrict__ b, int nb) {
  int i = blockIdx.x * blockDim.x + threadIdx.x;
  int stride = gridDim.x * blockDim.x;
  for (int j = i; j < na; j += stride) a[j] = 0;
  for (int j = i; j < nb; j += stride) b[j] = 0;
}

// ---------------------------------------------------------------------------
// graph preprocessing: degrees + per-edge rank, norm, CSR-by-dst
// ---------------------------------------------------------------------------
__global__ void count_rank_kernel(const int* __restrict__ dst, int E,
                                  int* __restrict__ deg, int* __restrict__ rank) {
  int i = blockIdx.x * blockDim.x + threadIdx.x;
  if (i < E) rank[i] = atomicAdd(&deg[dst[i]], 1);
}

__global__ void dinv_kernel(const int* __restrict__ deg, int n, float* __restrict__ dinv) {
  int i = blockIdx.x * blockDim.x + threadIdx.x;
  if (i < n) dinv[i] = 1.0f / sqrtf((float)(deg[i] + 1));  // +1 self-loop
}

// block-wise exclusive scan; also emits per-block total
__global__ void scan_block_kernel(const int* __restrict__ in, int n,
                                  int* __restrict__ out_excl, int* __restrict__ bsum) {
  __shared__ int sh[TPB];
  int t = threadIdx.x;
  int i = blockIdx.x * TPB + t;
  int v = (i < n) ? in[i] : 0;
  sh[t] = v;
  __syncthreads();
  for (int off = 1; off < TPB; off <<= 1) {
    int x = (t >= off) ? sh[t - off] : 0;
    __syncthreads();
    sh[t] += x;
    __syncthreads();
  }
  if (i < n) out_excl[i] = sh[t] - v;          // exclusive
  if (t == TPB - 1 && bsum != nullptr) bsum[blockIdx.x] = sh[t];
}

__global__ void scan_fixup_kernel(int* __restrict__ rs, const int* __restrict__ boff,
                                  int n, int total) {
  int i = blockIdx.x * TPB + threadIdx.x;
  if (i < n) rs[i] += boff[blockIdx.x];
  else if (i == n) rs[n] = total;
}

// atomic-free placement: col[rs[d] + rank[i]] = src[i]
__global__ void fill_kernel(const int* __restrict__ src, const int* __restrict__ dst,
                            const int* __restrict__ rank, const int* __restrict__ rs,
                            int E, int* __restrict__ col) {
  int i = blockIdx.x * blockDim.x + threadIdx.x;
  if (i < E) {
    int d = dst[i];
    col[rs[d] + rank[i]] = src[i];
  }
}

// ---------------------------------------------------------------------------
// W prep: wt[c][k] = bf16(W[k][c])   (128x128, one-shot, L1-resident after)
// ---------------------------------------------------------------------------
__global__ void wtrans_kernel(const float* __restrict__ W, ushort16* __restrict__ wt) {
  int i = blockIdx.x * blockDim.x + threadIdx.x;   // 0..16383
  int k = i >> 7;
  int c = i & 127;
  wt[(size_t)c * 128 + k] = f2bf(W[i]);
}

// ---------------------------------------------------------------------------
// MFMA GEMM: zws[N,128](bf16) = dinv[r] * (A[N,128](f32->bf16) @ W(bf16))
// 64 rows/block, 4 waves x 16 rows. mfma_f32_16x16x32_bf16:
//   A-frag: lane holds A[row=lane&15][k=(lane>>4)*8+j]  (16B contiguous in LDS)
//   B-frag: lane holds W[k=(lane>>4)*8+j][col=lane&15]  (16B contiguous in wt)
//   D:      col=lane&15, row=(lane>>4)*4+reg            (verified m89 layout)
// ---------------------------------------------------------------------------
__global__ __launch_bounds__(256) void gemm_mfma_kernel(
    const float* __restrict__ A, const ushort16* __restrict__ wt,
    const float* __restrict__ dinv, ushort16* __restrict__ out, int nrows) {
  __shared__ ushort16 Abf[64][128];   // 16 KB bf16 A-tile; reused as out staging
  int t = threadIdx.x;
  int r0 = blockIdx.x * 64;

  // stage A (f32 global) -> bf16 LDS
  {
    const float4* __restrict__ A4 = (const float4*)A;
#pragma unroll
    for (int i = 0; i < 8; ++i) {
      int idx = t + 256 * i;        // 0..2047
      int r = idx >> 5;             // 0..63
      int cc = idx & 31;            // float4 index within row
      float4 v = make_float4(0.f, 0.f, 0.f, 0.f);
      if (r0 + r < nrows) v = A4[(size_t)(r0 + r) * 32 + cc];
      ushort4 p;
      p.x = f2bf(v.x); p.y = f2bf(v.y); p.z = f2bf(v.z); p.w = f2bf(v.w);
      *(ushort4*)&Abf[r][cc * 4] = p;
    }
  }
  __syncthreads();

  int wave = t >> 6;
  int lane = t & 63;
  int lrow = lane & 15;
  int kg = lane >> 4;               // 0..3
  int rBase = wave * 16;            // 16 rows per wave

  f32x4 acc[8];
#pragma unroll
  for (int ct = 0; ct < 8; ++ct) acc[ct] = (f32x4){0.f, 0.f, 0.f, 0.f};

#pragma unroll
  for (int ks = 0; ks < 4; ++ks) {                 // K = 4 x 32
    bf16x8 af = *(const bf16x8*)&Abf[rBase + lrow][ks * 32 + kg * 8];
#pragma unroll
    for (int ct = 0; ct < 8; ++ct) {               // 8 col-tiles of 16
      bf16x8 bfr = *(const bf16x8*)&wt[(size_t)(ct * 16 + lrow) * 128 + ks * 32 + kg * 8];
      acc[ct] = __builtin_amdgcn_mfma_f32_16x16x32_bf16(af, bfr, acc[ct], 0, 0, 0);
    }
  }

  __syncthreads();   // all waves done reading Abf as input

  // scale by dinv, convert to bf16, stage into Abf as the output tile
#pragma unroll
  for (int reg = 0; reg < 4; ++reg) {
    int rl = rBase + kg * 4 + reg;                 // local row (D layout)
    int grow = r0 + rl;
    float di = (grow < nrows) ? dinv[grow] : 0.f;
#pragma unroll
    for (int ct = 0; ct < 8; ++ct) {
      Abf[rl][ct * 16 + lrow] = f2bf(di * acc[ct][reg]);
    }
  }
  __syncthreads();

  // coalesced copy LDS -> global (uint4)
  {
#pragma unroll
    for (int i = 0; i < 4; ++i) {
      int idx = t + 256 * i;        // 0..1023
      int r = idx >> 4;             // 0..63
      int cc = idx & 15;            // uint4 index within 256B row
      if (r0 + r < nrows)
        ((uint4*)&out[(size_t)(r0 + r) * 128])[cc] = ((const uint4*)&Abf[r][0])[cc];
    }
  }
}

// ---------------------------------------------------------------------------
// aggregation (R7 proven version): out[n] = prelu( dinv[n]*( zws[n] + sum ) + b )
// one wave per node; wave-cooperative col staging, uniform shfl broadcast.
// ---------------------------------------------------------------------------
__global__ __launch_bounds__(256) void aggregate_kernel(
    const ushort16* __restrict__ zws, const int* __restrict__ rs,
    const int* __restrict__ col,
    const float* __restrict__ dinv, const float* __restrict__ bias,
    const float* __restrict__ alpha, float* __restrict__ out, int nrows) {
  int wid = threadIdx.x >> 6;
  int lane = threadIdx.x & 63;
  int node = blockIdx.x * 4 + wid;
  if (node >= nrows) return;
  int c = lane * 2;

  uint32 pv = *(const uint32*)&zws[(size_t)node * 128 + c];
  float accx = bflo(pv), accy = bfhi(pv);

  int e0 = rs[node], e1 = rs[node + 1];
  for (int base = e0; base < e1; base += 64) {
    int nb = e1 - base; if (nb > 64) nb = 64;
    int colv = (base + lane < e1) ? col[base + lane] : 0;   // one coalesced load
    int j = 0;
    for (; j + 8 <= nb; j += 8) {
      int s0 = __shfl(colv, j + 0);
      int s1 = __shfl(colv, j + 1);
      int s2 = __shfl(colv, j + 2);
      int s3 = __shfl(colv, j + 3);
      int s4 = __shfl(colv, j + 4);
      int s5 = __shfl(colv, j + 5);
      int s6 = __shfl(colv, j + 6);
      int s7 = __shfl(colv, j + 7);
      uint32 p0 = *(const uint32*)&zws[(size_t)s0 * 128 + c];
      uint32 p1 = *(const uint32*)&zws[(size_t)s1 * 128 + c];
      uint32 p2 = *(const uint32*)&zws[(size_t)s2 * 128 + c];
      uint32 p3 = *(const uint32*)&zws[(size_t)s3 * 128 + c];
      uint32 p4 = *(const uint32*)&zws[(size_t)s4 * 128 + c];
      uint32 p5 = *(const uint32*)&zws[(size_t)s5 * 128 + c];
      uint32 p6 = *(const uint32*)&zws[(size_t)s6 * 128 + c];
      uint32 p7 = *(const uint32*)&zws[(size_t)s7 * 128 + c];
      accx += bflo(p0) + bflo(p1) + bflo(p2) + bflo(p3)
            + bflo(p4) + bflo(p5) + bflo(p6) + bflo(p7);
      accy += bfhi(p0) + bfhi(p1) + bfhi(p2) + bfhi(p3)
            + bfhi(p4) + bfhi(p5) + bfhi(p6) + bfhi(p7);
    }
    for (; j < nb; ++j) {
      int s = __shfl(colv, j);
      uint32 p = *(const uint32*)&zws[(size_t)s * 128 + c];
      accx += bflo(p);
      accy += bfhi(p);
    }
  }

  float di = dinv[node];
  float2 b = *(const float2*)&bias[c];
  float2 al = *(const float2*)&alpha[c];
  float zx = di * accx + b.x, zy = di * accy + b.y;
  zx = zx > 0.f ? zx : al.x * zx;
  zy = zy > 0.f ? zy : al.y * zy;
  float2 r; r.x = zx; r.y = zy;
  *(float2*)&out[(size_t)node * 128 + c] = r;
}

// ---------------------------------------------------------------------------
// pooling: g[gi] = [ sum_{batch[n]==gi} z1[n] | sum z2[n] ]  (batch sorted)
// ---------------------------------------------------------------------------
__global__ __launch_bounds__(256) void pool_kernel(const float* __restrict__ z1,
                                                   const float* __restrict__ z2,
                                                   const int* __restrict__ batch, int n,
                                                   float* __restrict__ g) {
  int r0 = blockIdx.x * PROWS;
  int t = threadIdx.x;
  __shared__ int bsh[PROWS];
  int rmax = n - r0; if (rmax > PROWS) rmax = PROWS;
  if (t < PROWS && t < rmax) bsh[t] = batch[r0 + t];
  __syncthreads();

  int c = t & 127;
  const float* __restrict__ src = (t < 128) ? z1 : z2;
  float acc = 0.f;
  int cur = bsh[0];
  for (int i = 0; i < rmax; ++i) {
    int b = bsh[i];
    if (b != cur) {
      atomicAdd(&g[(size_t)cur * 256 + t], acc);
      acc = 0.f;
      cur = b;
    }
    acc += src[(size_t)(r0 + i) * 128 + c];
  }
  atomicAdd(&g[(size_t)cur * 256 + t], acc);
}

// ---------------------------------------------------------------------------
// launcher
// ---------------------------------------------------------------------------
extern "C" void kernel_launch(void* const* d_in, const int* in_sizes, int n_in,
                              void* d_out, int out_size, void* d_ws, size_t ws_size,
                              hipStream_t stream) {
  const float* x     = (const float*)d_in[0];
  const int*   ei    = (const int*)d_in[1];
  const int*   batch = (const int*)d_in[2];
  const float* W0    = (const float*)d_in[3];
  const float* b0    = (const float*)d_in[4];
  const float* a0    = (const float*)d_in[5];
  const float* W1    = (const float*)d_in[6];
  const float* b1    = (const float*)d_in[7];
  const float* a1    = (const float*)d_in[8];
  float* out = (float*)d_out;

  const int N = in_sizes[0] / 128;
  const int E = in_sizes[1] / 2;
  const int G = (out_size - N * 128) / 256;

  const int* src  = ei;       // edge_index[0]
  const int* dstp = ei + E;   // edge_index[1]

  // workspace layout (4-byte words)
  int* w = (int*)d_ws;
  size_t o = 0;
  int*      deg    = w + o; o += (size_t)N;
  int*      rs     = w + o; o += (size_t)((N + 1 + 3) & ~3);
  int*      bsum   = w + o; o += 256;
  int*      boff   = w + o; o += 256;
  int*      col    = w + o; o += (size_t)E;
  int*      rank   = w + o; o += (size_t)E;
  float*    dinv   = (float*)(w + o); o += (size_t)N;
  ushort16* wt0    = (ushort16*)(w + o); o += 8192;             // bf16 W0^T
  ushort16* wt1    = (ushort16*)(w + o); o += 8192;             // bf16 W1^T
  ushort16* zws    = (ushort16*)(w + o); o += (size_t)N * 64;   // bf16 [N,128]
  float*    z1     = (float*)(w + o); o += (size_t)N * 128;
  (void)ws_size; (void)n_in;

  const int blkE = (E + TPB - 1) / TPB;
  const int blkN = (N + TPB - 1) / TPB;   // also #scan blocks (<= 256 for N<=65536)

  float* g = out + (size_t)N * 128;

  // zero deg + pooled-output region in one cheap dispatch
  zero2_kernel<<<512, TPB, 0, stream>>>(deg, N, (int*)g, G * 256);

  // W transposes (bf16), independent of graph prep
  wtrans_kernel<<<64, TPB, 0, stream>>>(W0, wt0);
  wtrans_kernel<<<64, TPB, 0, stream>>>(W1, wt1);

  // degrees + per-edge rank -> dinv
  count_rank_kernel<<<blkE, TPB, 0, stream>>>(dstp, E, deg, rank);
  dinv_kernel<<<blkN, TPB, 0, stream>>>(deg, N, dinv);

  // exclusive scan of deg -> row_start (rs), hierarchical
  scan_block_kernel<<<blkN, TPB, 0, stream>>>(deg, N, rs, bsum);
  scan_block_kernel<<<1, TPB, 0, stream>>>(bsum, blkN, boff, nullptr);
  scan_fixup_kernel<<<(N + TPB) / TPB, TPB, 0, stream>>>(rs, boff, N, E);

  // CSR fill (atomic-free)
  fill_kernel<<<blkE, TPB, 0, stream>>>(src, dstp, rank, rs, E, col);

  // layer 0: zws = bf16(dinv * (x @ W0)) ; z1 = prelu(dinv*(zws_self + sum) + b0)
  gemm_mfma_kernel<<<(N + 63) / 64, 256, 0, stream>>>(x, wt0, dinv, zws, N);
  aggregate_kernel<<<(N + 3) / 4, 256, 0, stream>>>(zws, rs, col, dinv, b0, a0, z1, N);

  // layer 1
  gemm_mfma_kernel<<<(N + 63) / 64, 256, 0, stream>>>(z1, wt1, dinv, zws, N);
  aggregate_kernel<<<(N + 3) / 4, 256, 0, stream>>>(zws, rs, col, dinv, b1, a1, out, N);

  // pooling -> g
  pool_kernel<<<(N + PROWS - 1) / PROWS, 256, 0, stream>>>(z1, out, batch, N, g);
}

// Round 12
// 196.453 us; speedup vs baseline: 1.1730x; 1.0524x over previous
//
#include <hip/hip_runtime.h>

#define TPB 256
#define PROWS 32

typedef unsigned int uint32;
typedef unsigned short ushort16;

typedef __attribute__((ext_vector_type(8))) short bf16x8;
typedef __attribute__((ext_vector_type(4))) float f32x4;

// ---------------------------------------------------------------------------
// helpers
// ---------------------------------------------------------------------------
__device__ __forceinline__ unsigned short f2bf(float f) {
  union { float f; unsigned int i; } c; c.f = f;
  unsigned int r = c.i + 0x7fffu + ((c.i >> 16) & 1u);   // RNE
  return (unsigned short)(r >> 16);
}

__device__ __forceinline__ float bflo(uint32 p) {   // low bf16 of packed pair
  union { unsigned int i; float f; } c; c.i = p << 16; return c.f;
}
__device__ __forceinline__ float bfhi(uint32 p) {   // high bf16 of packed pair
  union { unsigned int i; float f; } c; c.i = p & 0xffff0000u; return c.f;
}

// fused prep: zero deg + pooled output, bf16-transpose both W (one dispatch)
__global__ void prep_kernel(int* __restrict__ deg, int N,
                            int* __restrict__ g, int ng,
                            const float* __restrict__ W0, ushort16* __restrict__ wt0,
                            const float* __restrict__ W1, ushort16* __restrict__ wt1) {
  int i = blockIdx.x * blockDim.x + threadIdx.x;
  int stride = gridDim.x * blockDim.x;
  for (int j = i; j < N; j += stride) deg[j] = 0;
  for (int j = i; j < ng; j += stride) g[j] = 0;
  for (int j = i; j < 16384; j += stride) {
    int k = j >> 7, c = j & 127;
    wt0[(size_t)c * 128 + k] = f2bf(W0[j]);
    wt1[(size_t)c * 128 + k] = f2bf(W1[j]);
  }
}

// ---------------------------------------------------------------------------
// graph preprocessing: degrees + per-edge rank, norm, CSR-by-dst
// ---------------------------------------------------------------------------
__global__ void count_rank_kernel(const int* __restrict__ dst, int E,
                                  int* __restrict__ deg, int* __restrict__ rank) {
  int i = blockIdx.x * blockDim.x + threadIdx.x;
  if (i < E) rank[i] = atomicAdd(&deg[dst[i]], 1);
}

// block-wise exclusive scan; also emits per-block total; pass 1 also emits dinv
__global__ void scan_block_kernel(const int* __restrict__ in, int n,
                                  int* __restrict__ out_excl, int* __restrict__ bsum,
                                  float* __restrict__ dinv) {
  __shared__ int sh[TPB];
  int t = threadIdx.x;
  int i = blockIdx.x * TPB + t;
  int v = (i < n) ? in[i] : 0;
  if (dinv != nullptr && i < n) dinv[i] = 1.0f / sqrtf((float)(v + 1));  // +1 self-loop
  sh[t] = v;
  __syncthreads();
  for (int off = 1; off < TPB; off <<= 1) {
    int x = (t >= off) ? sh[t - off] : 0;
    __syncthreads();
    sh[t] += x;
    __syncthreads();
  }
  if (i < n) out_excl[i] = sh[t] - v;          // exclusive
  if (t == TPB - 1 && bsum != nullptr) bsum[blockIdx.x] = sh[t];
}

__global__ void scan_fixup_kernel(int* __restrict__ rs, const int* __restrict__ boff,
                                  int n, int total) {
  int i = blockIdx.x * TPB + threadIdx.x;
  if (i < n) rs[i] += boff[blockIdx.x];
  else if (i == n) rs[n] = total;
}

// atomic-free placement: col[rs[d] + rank[i]] = src[i]
__global__ void fill_kernel(const int* __restrict__ src, const int* __restrict__ dst,
                            const int* __restrict__ rank, const int* __restrict__ rs,
                            int E, int* __restrict__ col) {
  int i = blockIdx.x * blockDim.x + threadIdx.x;
  if (i < E) {
    int d = dst[i];
    col[rs[d] + rank[i]] = src[i];
  }
}

// ---------------------------------------------------------------------------
// MFMA GEMM (R11 proven): zws[N,128](bf16) = dinv[r] * (A @ W)
// ---------------------------------------------------------------------------
__global__ __launch_bounds__(256) void gemm_mfma_kernel(
    const float* __restrict__ A, const ushort16* __restrict__ wt,
    const float* __restrict__ dinv, ushort16* __restrict__ out, int nrows) {
  __shared__ ushort16 Abf[64][128];   // 16 KB bf16 A-tile; reused as out staging
  int t = threadIdx.x;
  int r0 = blockIdx.x * 64;

  {
    const float4* __restrict__ A4 = (const float4*)A;
#pragma unroll
    for (int i = 0; i < 8; ++i) {
      int idx = t + 256 * i;        // 0..2047
      int r = idx >> 5;             // 0..63
      int cc = idx & 31;            // float4 index within row
      float4 v = make_float4(0.f, 0.f, 0.f, 0.f);
      if (r0 + r < nrows) v = A4[(size_t)(r0 + r) * 32 + cc];
      ushort4 p;
      p.x = f2bf(v.x); p.y = f2bf(v.y); p.z = f2bf(v.z); p.w = f2bf(v.w);
      *(ushort4*)&Abf[r][cc * 4] = p;
    }
  }
  __syncthreads();

  int wave = t >> 6;
  int lane = t & 63;
  int lrow = lane & 15;
  int kg = lane >> 4;               // 0..3
  int rBase = wave * 16;            // 16 rows per wave

  f32x4 acc[8];
#pragma unroll
  for (int ct = 0; ct < 8; ++ct) acc[ct] = (f32x4){0.f, 0.f, 0.f, 0.f};

#pragma unroll
  for (int ks = 0; ks < 4; ++ks) {                 // K = 4 x 32
    bf16x8 af = *(const bf16x8*)&Abf[rBase + lrow][ks * 32 + kg * 8];
#pragma unroll
    for (int ct = 0; ct < 8; ++ct) {               // 8 col-tiles of 16
      bf16x8 bfr = *(const bf16x8*)&wt[(size_t)(ct * 16 + lrow) * 128 + ks * 32 + kg * 8];
      acc[ct] = __builtin_amdgcn_mfma_f32_16x16x32_bf16(af, bfr, acc[ct], 0, 0, 0);
    }
  }

  __syncthreads();   // all waves done reading Abf as input

#pragma unroll
  for (int reg = 0; reg < 4; ++reg) {
    int rl = rBase + kg * 4 + reg;                 // local row (D layout)
    int grow = r0 + rl;
    float di = (grow < nrows) ? dinv[grow] : 0.f;
#pragma unroll
    for (int ct = 0; ct < 8; ++ct) {
      Abf[rl][ct * 16 + lrow] = f2bf(di * acc[ct][reg]);
    }
  }
  __syncthreads();

  {
#pragma unroll
    for (int i = 0; i < 4; ++i) {
      int idx = t + 256 * i;        // 0..1023
      int r = idx >> 4;             // 0..63
      int cc = idx & 15;            // uint4 index within 256B row
      if (r0 + r < nrows)
        ((uint4*)&out[(size_t)(r0 + r) * 128])[cc] = ((const uint4*)&Abf[r][0])[cc];
    }
  }
}

// ---------------------------------------------------------------------------
// aggregation: out[n] = prelu( dinv[n]*( zws[n] + sum_{e: dst=n} zws[col[e]] ) + b )
// one wave per node; wave-cooperative col staging. All groups 8-wide; the tail
// group is masked (clamped shfl index, x0 weight) so its 8 loads issue
// independently instead of a rolled 1-at-a-time remainder loop.
// ---------------------------------------------------------------------------
__global__ __launch_bounds__(256) void aggregate_kernel(
    const ushort16* __restrict__ zws, const int* __restrict__ rs,
    const int* __restrict__ col,
    const float* __restrict__ dinv, const float* __restrict__ bias,
    const float* __restrict__ alpha, float* __restrict__ out, int nrows) {
  int wid = threadIdx.x >> 6;
  int lane = threadIdx.x & 63;
  int node = blockIdx.x * 4 + wid;
  if (node >= nrows) return;
  int c = lane * 2;

  uint32 pv = *(const uint32*)&zws[(size_t)node * 128 + c];
  float accx = bflo(pv), accy = bfhi(pv);

  int e0 = rs[node], e1 = rs[node + 1];
  for (int base = e0; base < e1; base += 64) {
    int nb = e1 - base; if (nb > 64) nb = 64;
    int colv = (base + lane < e1) ? col[base + lane] : 0;   // one coalesced load
    int j = 0;
    for (; j + 8 <= nb; j += 8) {
      int s0 = __shfl(colv, j + 0);
      int s1 = __shfl(colv, j + 1);
      int s2 = __shfl(colv, j + 2);
      int s3 = __shfl(colv, j + 3);
      int s4 = __shfl(colv, j + 4);
      int s5 = __shfl(colv, j + 5);
      int s6 = __shfl(colv, j + 6);
      int s7 = __shfl(colv, j + 7);
      uint32 p0 = *(const uint32*)&zws[(size_t)s0 * 128 + c];
      uint32 p1 = *(const uint32*)&zws[(size_t)s1 * 128 + c];
      uint32 p2 = *(const uint32*)&zws[(size_t)s2 * 128 + c];
      uint32 p3 = *(const uint32*)&zws[(size_t)s3 * 128 + c];
      uint32 p4 = *(const uint32*)&zws[(size_t)s4 * 128 + c];
      uint32 p5 = *(const uint32*)&zws[(size_t)s5 * 128 + c];
      uint32 p6 = *(const uint32*)&zws[(size_t)s6 * 128 + c];
      uint32 p7 = *(const uint32*)&zws[(size_t)s7 * 128 + c];
      accx += bflo(p0) + bflo(p1) + bflo(p2) + bflo(p3)
            + bflo(p4) + bflo(p5) + bflo(p6) + bflo(p7);
      accy += bfhi(p0) + bfhi(p1) + bfhi(p2) + bfhi(p3)
            + bfhi(p4) + bfhi(p5) + bfhi(p6) + bfhi(p7);
    }
    if (j < nb) {   // masked 8-wide tail: clamped index, zero weight for invalid
      int last = nb - 1;
      int i0 = j + 0, i1 = j + 1, i2 = j + 2, i3 = j + 3;
      int i4 = j + 4, i5 = j + 5, i6 = j + 6, i7 = j + 7;
      int s0 = __shfl(colv, i0 < last ? i0 : last);
      int s1 = __shfl(colv, i1 < last ? i1 : last);
      int s2 = __shfl(colv, i2 < last ? i2 : last);
      int s3 = __shfl(colv, i3 < last ? i3 : last);
      int s4 = __shfl(colv, i4 < last ? i4 : last);
      int s5 = __shfl(colv, i5 < last ? i5 : last);
      int s6 = __shfl(colv, i6 < last ? i6 : last);
      int s7 = __shfl(colv, i7 < last ? i7 : last);
      float m0 = (i0 < nb) ? 1.f : 0.f, m1 = (i1 < nb) ? 1.f : 0.f;
      float m2 = (i2 < nb) ? 1.f : 0.f, m3 = (i3 < nb) ? 1.f : 0.f;
      float m4 = (i4 < nb) ? 1.f : 0.f, m5 = (i5 < nb) ? 1.f : 0.f;
      float m6 = (i6 < nb) ? 1.f : 0.f, m7 = (i7 < nb) ? 1.f : 0.f;
      uint32 p0 = *(const uint32*)&zws[(size_t)s0 * 128 + c];
      uint32 p1 = *(const uint32*)&zws[(size_t)s1 * 128 + c];
      uint32 p2 = *(const uint32*)&zws[(size_t)s2 * 128 + c];
      uint32 p3 = *(const uint32*)&zws[(size_t)s3 * 128 + c];
      uint32 p4 = *(const uint32*)&zws[(size_t)s4 * 128 + c];
      uint32 p5 = *(const uint32*)&zws[(size_t)s5 * 128 + c];
      uint32 p6 = *(const uint32*)&zws[(size_t)s6 * 128 + c];
      uint32 p7 = *(const uint32*)&zws[(size_t)s7 * 128 + c];
      accx += m0 * bflo(p0) + m1 * bflo(p1) + m2 * bflo(p2) + m3 * bflo(p3)
            + m4 * bflo(p4) + m5 * bflo(p5) + m6 * bflo(p6) + m7 * bflo(p7);
      accy += m0 * bfhi(p0) + m1 * bfhi(p1) + m2 * bfhi(p2) + m3 * bfhi(p3)
            + m4 * bfhi(p4) + m5 * bfhi(p5) + m6 * bfhi(p6) + m7 * bfhi(p7);
    }
  }

  float di = dinv[node];
  float2 b = *(const float2*)&bias[c];
  float2 al = *(const float2*)&alpha[c];
  float zx = di * accx + b.x, zy = di * accy + b.y;
  zx = zx > 0.f ? zx : al.x * zx;
  zy = zy > 0.f ? zy : al.y * zy;
  float2 r; r.x = zx; r.y = zy;
  *(float2*)&out[(size_t)node * 128 + c] = r;
}

// ---------------------------------------------------------------------------
// pooling: g[gi] = [ sum_{batch[n]==gi} z1[n] | sum z2[n] ]  (batch sorted)
// ---------------------------------------------------------------------------
__global__ __launch_bounds__(256) void pool_kernel(const float* __restrict__ z1,
                                                   const float* __restrict__ z2,
                                                   const int* __restrict__ batch, int n,
                                                   float* __restrict__ g) {
  int r0 = blockIdx.x * PROWS;
  int t = threadIdx.x;
  __shared__ int bsh[PROWS];
  int rmax = n - r0; if (rmax > PROWS) rmax = PROWS;
  if (t < PROWS && t < rmax) bsh[t] = batch[r0 + t];
  __syncthreads();

  int c = t & 127;
  const float* __restrict__ src = (t < 128) ? z1 : z2;
  float acc = 0.f;
  int cur = bsh[0];
  for (int i = 0; i < rmax; ++i) {
    int b = bsh[i];
    if (b != cur) {
      atomicAdd(&g[(size_t)cur * 256 + t], acc);
      acc = 0.f;
      cur = b;
    }
    acc += src[(size_t)(r0 + i) * 128 + c];
  }
  atomicAdd(&g[(size_t)cur * 256 + t], acc);
}

// ---------------------------------------------------------------------------
// launcher
// ---------------------------------------------------------------------------
extern "C" void kernel_launch(void* const* d_in, const int* in_sizes, int n_in,
                              void* d_out, int out_size, void* d_ws, size_t ws_size,
                              hipStream_t stream) {
  const float* x     = (const float*)d_in[0];
  const int*   ei    = (const int*)d_in[1];
  const int*   batch = (const int*)d_in[2];
  const float* W0    = (const float*)d_in[3];
  const float* b0    = (const float*)d_in[4];
  const float* a0    = (const float*)d_in[5];
  const float* W1    = (const float*)d_in[6];
  const float* b1    = (const float*)d_in[7];
  const float* a1    = (const float*)d_in[8];
  float* out = (float*)d_out;

  const int N = in_sizes[0] / 128;
  const int E = in_sizes[1] / 2;
  const int G = (out_size - N * 128) / 256;

  const int* src  = ei;       // edge_index[0]
  const int* dstp = ei + E;   // edge_index[1]

  // workspace layout (4-byte words)
  int* w = (int*)d_ws;
  size_t o = 0;
  int*      deg    = w + o; o += (size_t)N;
  int*      rs     = w + o; o += (size_t)((N + 1 + 3) & ~3);
  int*      bsum   = w + o; o += 256;
  int*      boff   = w + o; o += 256;
  int*      col    = w + o; o += (size_t)E;
  int*      rank   = w + o; o += (size_t)E;
  float*    dinv   = (float*)(w + o); o += (size_t)N;
  ushort16* wt0    = (ushort16*)(w + o); o += 8192;             // bf16 W0^T
  ushort16* wt1    = (ushort16*)(w + o); o += 8192;             // bf16 W1^T
  ushort16* zws    = (ushort16*)(w + o); o += (size_t)N * 64;   // bf16 [N,128]
  float*    z1     = (float*)(w + o); o += (size_t)N * 128;
  (void)ws_size; (void)n_in;

  const int blkE = (E + TPB - 1) / TPB;
  const int blkN = (N + TPB - 1) / TPB;   // also #scan blocks (<= 256 for N<=65536)

  float* g = out + (size_t)N * 128;

  // fused prep: zero deg + g, transpose both W to bf16
  prep_kernel<<<512, TPB, 0, stream>>>(deg, N, (int*)g, G * 256, W0, wt0, W1, wt1);

  // degrees + per-edge rank
  count_rank_kernel<<<blkE, TPB, 0, stream>>>(dstp, E, deg, rank);

  // exclusive scan of deg -> row_start (rs), hierarchical; pass 1 also emits dinv
  scan_block_kernel<<<blkN, TPB, 0, stream>>>(deg, N, rs, bsum, dinv);
  scan_block_kernel<<<1, TPB, 0, stream>>>(bsum, blkN, boff, nullptr, nullptr);
  scan_fixup_kernel<<<(N + TPB) / TPB, TPB, 0, stream>>>(rs, boff, N, E);

  // CSR fill (atomic-free)
  fill_kernel<<<blkE, TPB, 0, stream>>>(src, dstp, rank, rs, E, col);

  // layer 0: zws = bf16(dinv * (x @ W0)) ; z1 = prelu(dinv*(zws_self + sum) + b0)
  gemm_mfma_kernel<<<(N + 63) / 64, 256, 0, stream>>>(x, wt0, dinv, zws, N);
  aggregate_kernel<<<(N + 3) / 4, 256, 0, stream>>>(zws, rs, col, dinv, b0, a0, z1, N);

  // layer 1
  gemm_mfma_kernel<<<(N + 63) / 64, 256, 0, stream>>>(z1, wt1, dinv, zws, N);
  aggregate_kernel<<<(N + 3) / 4, 256, 0, stream>>>(zws, rs, col, dinv, b1, a1, out, N);

  // pooling -> g
  pool_kernel<<<(N + PROWS - 1) / PROWS, 256, 0, stream>>>(z1, out, batch, N, g);
}